// Round 4
// baseline (101.083 us; speedup 1.0000x reference)
//
#include <hip/hip_runtime.h>

// B=2, N=24, E=128, H=8, D=16
#define BB 2
#define NN 24
#define EE 128
#define HH 8
#define DD 16
#define ROWS (BB * NN * NN)   // 1152
#define LKP 132               // padded LDS row stride (floats) for score slices

// ---------------------------------------------------------------------------
// K0: transpose the five 128x128 weight matrices into ws so later reads are
// coalesced (WT[k][j], lane = j). LDS 32x33 tile transpose, 80 blocks.
// wt layout: [0]=WlkT [1]=WrkT [2]=WlvT [3]=WrvT [4]=WoutT, each 16384 floats.
// ---------------------------------------------------------------------------
__global__ __launch_bounds__(256) void transpose_kernel(
    const float* __restrict__ W_lk, const float* __restrict__ W_rk,
    const float* __restrict__ W_lv, const float* __restrict__ W_rv,
    const float* __restrict__ W_out, float* __restrict__ wt)
{
    __shared__ float ld[32][33];
    const int blk  = blockIdx.x;
    const int mat  = blk / 16;
    const int tile = blk % 16;
    const int ti = tile >> 2, tj = tile & 3;
    const float* W;
    switch (mat) {
        case 0: W = W_lk; break; case 1: W = W_rk; break;
        case 2: W = W_lv; break; case 3: W = W_rv; break;
        default: W = W_out; break;
    }
    float* WT = wt + mat * 16384;
    const int t = threadIdx.x;
    #pragma unroll
    for (int e = t; e < 1024; e += 256) {
        const int r = e >> 5, c = e & 31;
        ld[r][c] = W[(ti * 32 + r) * EE + tj * 32 + c];   // coalesced read
    }
    __syncthreads();
    #pragma unroll
    for (int e = t; e < 1024; e += 256) {
        const int c = e >> 5, r = e & 31;
        WT[(tj * 32 + c) * EE + ti * 32 + r] = ld[r][c];  // coalesced write
    }
}

// ---------------------------------------------------------------------------
// K1: projections Y = X @ W^T via transposed weights (coalesced).
// Grid 1152 = 4 mats x 288 tiles (4 rows). 256 thr: j = t&127, rg = t>>7
// -> 2 rows per thread. No LDS, no syncthreads. X loads are wave-uniform
// float4 broadcasts; WT loads are coalesced (lane = j).
// ---------------------------------------------------------------------------
__global__ __launch_bounds__(256) void proj_kernel(
    const float* __restrict__ query, const float* __restrict__ key_t,
    const float* __restrict__ value, const float* __restrict__ wt,
    float* __restrict__ proj)
{
    const int blk  = blockIdx.x;
    const int mat  = blk / 288;
    const int tile = blk % 288;
    const int t  = threadIdx.x;
    const int j  = t & 127;
    const int rg = t >> 7;
    const float* X  = (mat == 0) ? query : (mat == 1) ? key_t : value;
    const float* WT = wt + mat * 16384;
    float* Y = proj + (size_t)mat * ROWS * EE;
    const int r0 = tile * 4 + rg * 2;
    const float* xb = X + (size_t)r0 * EE;

    float a0 = 0.f, a1 = 0.f;
    #pragma unroll 8
    for (int kk = 0; kk < 32; ++kk) {
        const float4 x0 = *(const float4*)(xb + kk * 4);
        const float4 x1 = *(const float4*)(xb + EE + kk * 4);
        const float w0 = WT[(kk * 4 + 0) * EE + j];
        const float w1 = WT[(kk * 4 + 1) * EE + j];
        const float w2 = WT[(kk * 4 + 2) * EE + j];
        const float w3 = WT[(kk * 4 + 3) * EE + j];
        a0 += w0 * x0.x + w1 * x0.y + w2 * x0.z + w3 * x0.w;
        a1 += w0 * x1.x + w1 * x1.y + w2 * x1.z + w3 * x1.w;
    }
    Y[(size_t)r0 * EE + j]       = a0;
    Y[(size_t)(r0 + 1) * EE + j] = a1;
}

// ---------------------------------------------------------------------------
// K2: attention core + fused out-projection. One block (256 thr = 4 waves)
// per (b,x,y); 1152 blocks -> 4608 waves (18/CU).
//  stage: lkS/rkS (24x128, padded rows) coalesced into LDS
//  A+B  : wave 0 computes 192 scores (3/lane from LDS) + softmax in-register
//         (xor-shfl 8/16/32), publishes att[24][8] to LDS
//  C    : wave w owns dims [32w,32w+32); lane half handles 12 a's;
//         shfl_xor(32) combine -> xloc[128] in LDS
//  D    : j = t>>1, i-half = t&1; coalesced WoutT reads; shfl_xor(1) combine
// ---------------------------------------------------------------------------
__global__ __launch_bounds__(256) void attn_kernel(
    const float* __restrict__ proj, const float* __restrict__ wt,
    float* __restrict__ out)
{
    __shared__ float lkS[NN][LKP];
    __shared__ float rkS[NN][LKP];
    __shared__ float attS[NN][HH];
    __shared__ float xloc[EE];

    const int t    = threadIdx.x;
    const int lane = t & 63;
    const int w    = t >> 6;
    const int blk  = blockIdx.x;          // (b*24 + x)*24 + y
    const int y  = blk % NN;
    const int bx = blk / NN;              // b*24 + x
    const int b  = bx / NN;

    const float* lk = proj + 0 * (size_t)ROWS * EE;
    const float* rk = proj + 1 * (size_t)ROWS * EE;
    const float* lv = proj + 2 * (size_t)ROWS * EE;
    const float* rv = proj + 3 * (size_t)ROWS * EE;
    const float* WoutT = wt + 4 * 16384;

    // ---- stage lk(b,x,*,:) and rk(b,*,y,:) into LDS (coalesced) ----
    const float4* lk4 = (const float4*)(lk + (size_t)(bx * NN) * EE);
    #pragma unroll
    for (int i = t; i < NN * EE / 4; i += 256) {   // 3 iterations
        const int a = i >> 5, c = i & 31;
        *(float4*)&lkS[a][c * 4] = lk4[i];
        const float4* r4 = (const float4*)(rk + (size_t)((b * NN + a) * NN + y) * EE);
        *(float4*)&rkS[a][c * 4] = r4[c];
    }
    __syncthreads();

    // ---- A+B: scores + softmax (wave 0 only), publish att to LDS ----
    if (w == 0) {
        float att[3];
        #pragma unroll
        for (int p = 0; p < 3; ++p) {
            const int il = lane + 64 * p;
            const int a  = il >> 3;
            const int h  = il & 7;
            float acc = 0.f;
            #pragma unroll
            for (int c = 0; c < 4; ++c) {
                const float4 u = *(const float4*)&lkS[a][h * DD + c * 4];
                const float4 v = *(const float4*)&rkS[a][h * DD + c * 4];
                acc += u.x * v.x + u.y * v.y + u.z * v.z + u.w * v.w;
            }
            att[p] = acc * 0.25f;         // 1/sqrt(16)
        }
        float m = fmaxf(att[0], fmaxf(att[1], att[2]));
        m = fmaxf(m, __shfl_xor(m, 8));
        m = fmaxf(m, __shfl_xor(m, 16));
        m = fmaxf(m, __shfl_xor(m, 32));
        float s = 0.f;
        #pragma unroll
        for (int p = 0; p < 3; ++p) { att[p] = __expf(att[p] - m); s += att[p]; }
        s += __shfl_xor(s, 8);
        s += __shfl_xor(s, 16);
        s += __shfl_xor(s, 32);
        const float inv = 1.f / s;
        #pragma unroll
        for (int p = 0; p < 3; ++p) {
            const int il = lane + 64 * p;
            attS[il >> 3][il & 7] = att[p] * inv;
        }
    }
    __syncthreads();

    // ---- C: weighted outer-product, wave w owns dims [32w, 32w+32) ----
    {
        const int dim = w * 32 + (lane & 31);
        const int a0  = (lane >> 5) * 12;          // 12 a's per half-wave
        const int hd  = dim >> 4;
        float acc = 0.f;
        #pragma unroll
        for (int aa = 0; aa < 12; ++aa) {
            const int a = a0 + aa;
            const float attv = attS[a][hd];
            acc += attv * lv[(size_t)(bx * NN + a) * EE + dim]
                        * rv[(size_t)((b * NN + a) * NN + y) * EE + dim];
        }
        acc += __shfl_xor(acc, 32);
        if (lane < 32) xloc[dim] = acc;
    }
    __syncthreads();

    // ---- D: fused out-projection ----
    {
        const int j    = t >> 1;
        const int half = t & 1;
        float acc = 0.f;
        #pragma unroll 16
        for (int ii = 0; ii < 64; ++ii) {
            const int i = half * 64 + ii;
            acc += xloc[i] * WoutT[i * EE + j];
        }
        acc += __shfl_xor(acc, 1);
        if (half == 0) out[(size_t)blk * EE + j] = acc;
    }
}

extern "C" void kernel_launch(void* const* d_in, const int* in_sizes, int n_in,
                              void* d_out, int out_size, void* d_ws, size_t ws_size,
                              hipStream_t stream) {
    const float* query = (const float*)d_in[0];
    const float* key_t = (const float*)d_in[1];
    const float* value = (const float*)d_in[2];
    const float* W_lk  = (const float*)d_in[3];
    const float* W_rk  = (const float*)d_in[4];
    const float* W_lv  = (const float*)d_in[5];
    const float* W_rv  = (const float*)d_in[6];
    const float* W_out = (const float*)d_in[7];

    float* wt   = (float*)d_ws;                 // 5 * 16384 floats
    float* proj = wt + 5 * 16384;               // 4 * 1152 * 128 floats

    transpose_kernel<<<80, 256, 0, stream>>>(W_lk, W_rk, W_lv, W_rv, W_out, wt);
    proj_kernel<<<1152, 256, 0, stream>>>(query, key_t, value, wt, proj);
    attn_kernel<<<ROWS, 256, 0, stream>>>(proj, wt, (float*)d_out);
}

// Round 7
// 95.719 us; speedup vs baseline: 1.0560x; 1.0560x over previous
//
#include <hip/hip_runtime.h>
#include <hip/hip_cooperative_groups.h>

namespace cg = cooperative_groups;

// B=2, N=24, E=128, H=8, D=16
#define BB 2
#define NN 24
#define EE 128
#define HH 8
#define DD 16
#define ROWS (BB * NN * NN)   // 1152
#define CJOBS (ROWS / 4)      // 288 phase-C block jobs (4 waves per block)

// ---------------------------------------------------------------------------
// Fused cooperative kernel; ALL phases are grid-stride so any grid size is
// correct. wt: [0]=WlkT [1]=WrkT [2]=WlvT [3]=WrvT [4]=WoutT (16384 floats ea).
// ---------------------------------------------------------------------------
__global__ __launch_bounds__(256) void fused_kernel(
    const float* __restrict__ query, const float* __restrict__ key_t,
    const float* __restrict__ value,
    const float* __restrict__ W_lk, const float* __restrict__ W_rk,
    const float* __restrict__ W_lv, const float* __restrict__ W_rv,
    const float* __restrict__ W_out,
    float* __restrict__ wt, float* __restrict__ proj,
    float* __restrict__ out)
{
    cg::grid_group grid = cg::this_grid();
    __shared__ float ld[32][33];

    const int t    = threadIdx.x;
    const int nblk = gridDim.x;

    // ---------------- Phase A: weight transposes (80 tile jobs) ------------
    for (int job = blockIdx.x; job < 80; job += nblk) {
        const int mat  = job / 16;
        const int tile = job % 16;
        const int ti = tile >> 2, tj = tile & 3;
        const float* W;
        switch (mat) {
            case 0: W = W_lk; break; case 1: W = W_rk; break;
            case 2: W = W_lv; break; case 3: W = W_rv; break;
            default: W = W_out; break;
        }
        float* WT = wt + mat * 16384;
        __syncthreads();   // protect ld[] reuse across job iterations
        #pragma unroll
        for (int e = t; e < 1024; e += 256) {
            const int r = e >> 5, c = e & 31;
            ld[r][c] = W[(ti * 32 + r) * EE + tj * 32 + c];   // coalesced read
        }
        __syncthreads();
        #pragma unroll
        for (int e = t; e < 1024; e += 256) {
            const int c = e >> 5, r = e & 31;
            WT[(tj * 32 + c) * EE + ti * 32 + r] = ld[r][c];  // coalesced write
        }
    }
    grid.sync();

    // ---------------- Phase B: projections (1152 grid-stride jobs) ---------
    {
        const int j  = t & 127;
        const int rg = t >> 7;
        for (int job = blockIdx.x; job < 4 * 288; job += nblk) {
            const int mat  = job / 288;
            const int tile = job % 288;
            const float* X  = (mat == 0) ? query : (mat == 1) ? key_t : value;
            const float* WT = wt + mat * 16384;
            float* Y = proj + (size_t)mat * ROWS * EE;
            const int r0 = tile * 4 + rg * 2;
            const float* xb = X + (size_t)r0 * EE;

            float a0 = 0.f, a1 = 0.f;
            #pragma unroll 8
            for (int kk = 0; kk < 32; ++kk) {
                const float4 x0 = *(const float4*)(xb + kk * 4);
                const float4 x1 = *(const float4*)(xb + EE + kk * 4);
                const float w0 = WT[(kk * 4 + 0) * EE + j];
                const float w1 = WT[(kk * 4 + 1) * EE + j];
                const float w2 = WT[(kk * 4 + 2) * EE + j];
                const float w3 = WT[(kk * 4 + 3) * EE + j];
                a0 += w0 * x0.x + w1 * x0.y + w2 * x0.z + w3 * x0.w;
                a1 += w0 * x1.x + w1 * x1.y + w2 * x1.z + w3 * x1.w;
            }
            Y[(size_t)r0 * EE + j]       = a0;
            Y[(size_t)(r0 + 1) * EE + j] = a1;
        }
    }
    grid.sync();

    // ---------------- Phase C: attention + out-projection ------------------
    {
        const int lane = t & 63;
        const int w    = t >> 6;
        const float* lk = proj + 0 * (size_t)ROWS * EE;
        const float* rk = proj + 1 * (size_t)ROWS * EE;
        const float* lv = proj + 2 * (size_t)ROWS * EE;
        const float* rv = proj + 3 * (size_t)ROWS * EE;
        const float* WoutT = wt + 4 * 16384;

        for (int bj = blockIdx.x; bj < CJOBS; bj += nblk) {
            const int wj = bj * 4 + w;         // (b*24 + x)*24 + y
            const int y  = wj % NN;
            const int bx = wj / NN;            // b*24 + x
            const int b  = bx / NN;

            // A: scores (3 per lane; 8-lane groups read contiguous rows)
            float att[3];
            #pragma unroll
            for (int p = 0; p < 3; ++p) {
                const int il = lane + 64 * p;
                const int a  = il >> 3;
                const int h  = il & 7;
                const float4* lp = (const float4*)(lk + ((size_t)(bx * NN + a)) * EE + h * DD);
                const float4* rp = (const float4*)(rk + ((size_t)((b * NN + a) * NN + y)) * EE + h * DD);
                float acc = 0.f;
                #pragma unroll
                for (int c = 0; c < 4; ++c) {
                    const float4 u = lp[c], v = rp[c];
                    acc += u.x * v.x + u.y * v.y + u.z * v.z + u.w * v.w;
                }
                att[p] = acc * 0.25f;          // 1/sqrt(16)
            }

            // B: softmax over a within head groups (lanes with equal l&7)
            float m = fmaxf(att[0], fmaxf(att[1], att[2]));
            m = fmaxf(m, __shfl_xor(m, 8));
            m = fmaxf(m, __shfl_xor(m, 16));
            m = fmaxf(m, __shfl_xor(m, 32));
            float s = 0.f;
            #pragma unroll
            for (int p = 0; p < 3; ++p) { att[p] = __expf(att[p] - m); s += att[p]; }
            s += __shfl_xor(s, 8);
            s += __shfl_xor(s, 16);
            s += __shfl_xor(s, 32);
            const float inv = 1.f / s;
            #pragma unroll
            for (int p = 0; p < 3; ++p) att[p] *= inv;

            // C: weighted outer-product reduction over a (dims 2*lane, +1)
            const int h = lane >> 3;
            float xx = 0.f, xy = 0.f;
            #pragma unroll
            for (int a = 0; a < NN; ++a) {
                const float attv = __shfl(att[a >> 3], ((a & 7) << 3) | h);
                const float2 l2 = *(const float2*)(lv + ((size_t)(bx * NN + a)) * EE + lane * 2);
                const float2 r2 = *(const float2*)(rv + ((size_t)((b * NN + a) * NN + y)) * EE + lane * 2);
                xx += attv * l2.x * r2.x;
                xy += attv * l2.y * r2.y;
            }

            // D: fused out-projection (coalesced WoutT, shfl broadcast x)
            float ox = 0.f, oy = 0.f;
            #pragma unroll
            for (int i = 0; i < EE; ++i) {
                const float xv = __shfl((i & 1) ? xy : xx, i >> 1);
                const float2 w2 = *(const float2*)(WoutT + i * EE + lane * 2);
                ox += xv * w2.x;
                oy += xv * w2.y;
            }
            *(float2*)(out + (size_t)wj * EE + lane * 2) = make_float2(ox, oy);
        }
    }
}

// ------------------- fallback path: separate kernels -----------------------
__global__ __launch_bounds__(256) void transpose_kernel(
    const float* __restrict__ W_lk, const float* __restrict__ W_rk,
    const float* __restrict__ W_lv, const float* __restrict__ W_rv,
    const float* __restrict__ W_out, float* __restrict__ wt)
{
    __shared__ float ld[32][33];
    const int blk  = blockIdx.x;
    const int mat  = blk / 16;
    const int tile = blk % 16;
    const int ti = tile >> 2, tj = tile & 3;
    const float* W;
    switch (mat) {
        case 0: W = W_lk; break; case 1: W = W_rk; break;
        case 2: W = W_lv; break; case 3: W = W_rv; break;
        default: W = W_out; break;
    }
    float* WT = wt + mat * 16384;
    const int t = threadIdx.x;
    #pragma unroll
    for (int e = t; e < 1024; e += 256) {
        const int r = e >> 5, c = e & 31;
        ld[r][c] = W[(ti * 32 + r) * EE + tj * 32 + c];
    }
    __syncthreads();
    #pragma unroll
    for (int e = t; e < 1024; e += 256) {
        const int c = e >> 5, r = e & 31;
        WT[(tj * 32 + c) * EE + ti * 32 + r] = ld[r][c];
    }
}

__global__ __launch_bounds__(256) void proj_kernel(
    const float* __restrict__ query, const float* __restrict__ key_t,
    const float* __restrict__ value, const float* __restrict__ wt,
    float* __restrict__ proj)
{
    const int blk  = blockIdx.x;
    const int mat  = blk / 288;
    const int tile = blk % 288;
    const int t  = threadIdx.x;
    const int j  = t & 127;
    const int rg = t >> 7;
    const float* X  = (mat == 0) ? query : (mat == 1) ? key_t : value;
    const float* WT = wt + mat * 16384;
    float* Y = proj + (size_t)mat * ROWS * EE;
    const int r0 = tile * 4 + rg * 2;
    const float* xb = X + (size_t)r0 * EE;

    float a0 = 0.f, a1 = 0.f;
    #pragma unroll 8
    for (int kk = 0; kk < 32; ++kk) {
        const float4 x0 = *(const float4*)(xb + kk * 4);
        const float4 x1 = *(const float4*)(xb + EE + kk * 4);
        const float w0 = WT[(kk * 4 + 0) * EE + j];
        const float w1 = WT[(kk * 4 + 1) * EE + j];
        const float w2 = WT[(kk * 4 + 2) * EE + j];
        const float w3 = WT[(kk * 4 + 3) * EE + j];
        a0 += w0 * x0.x + w1 * x0.y + w2 * x0.z + w3 * x0.w;
        a1 += w0 * x1.x + w1 * x1.y + w2 * x1.z + w3 * x1.w;
    }
    Y[(size_t)r0 * EE + j]       = a0;
    Y[(size_t)(r0 + 1) * EE + j] = a1;
}

__global__ __launch_bounds__(64) void attn_kernel(
    const float* __restrict__ proj, const float* __restrict__ wt,
    float* __restrict__ out)
{
    const int lane = threadIdx.x;
    const int wj   = blockIdx.x;
    const int y  = wj % NN;
    const int bx = wj / NN;
    const int b  = bx / NN;

    const float* lk = proj + 0 * (size_t)ROWS * EE;
    const float* rk = proj + 1 * (size_t)ROWS * EE;
    const float* lv = proj + 2 * (size_t)ROWS * EE;
    const float* rv = proj + 3 * (size_t)ROWS * EE;
    const float* WoutT = wt + 4 * 16384;

    float att[3];
    #pragma unroll
    for (int p = 0; p < 3; ++p) {
        const int il = lane + 64 * p;
        const int a  = il >> 3;
        const int h  = il & 7;
        const float4* lp = (const float4*)(lk + ((size_t)(bx * NN + a)) * EE + h * DD);
        const float4* rp = (const float4*)(rk + ((size_t)((b * NN + a) * NN + y)) * EE + h * DD);
        float acc = 0.f;
        #pragma unroll
        for (int c = 0; c < 4; ++c) {
            const float4 u = lp[c], v = rp[c];
            acc += u.x * v.x + u.y * v.y + u.z * v.z + u.w * v.w;
        }
        att[p] = acc * 0.25f;
    }
    float m = fmaxf(att[0], fmaxf(att[1], att[2]));
    m = fmaxf(m, __shfl_xor(m, 8));
    m = fmaxf(m, __shfl_xor(m, 16));
    m = fmaxf(m, __shfl_xor(m, 32));
    float s = 0.f;
    #pragma unroll
    for (int p = 0; p < 3; ++p) { att[p] = __expf(att[p] - m); s += att[p]; }
    s += __shfl_xor(s, 8);
    s += __shfl_xor(s, 16);
    s += __shfl_xor(s, 32);
    const float inv = 1.f / s;
    #pragma unroll
    for (int p = 0; p < 3; ++p) att[p] *= inv;

    const int h = lane >> 3;
    float xx = 0.f, xy = 0.f;
    #pragma unroll
    for (int a = 0; a < NN; ++a) {
        const float attv = __shfl(att[a >> 3], ((a & 7) << 3) | h);
        const float2 l2 = *(const float2*)(lv + ((size_t)(bx * NN + a)) * EE + lane * 2);
        const float2 r2 = *(const float2*)(rv + ((size_t)((b * NN + a) * NN + y)) * EE + lane * 2);
        xx += attv * l2.x * r2.x;
        xy += attv * l2.y * r2.y;
    }
    float ox = 0.f, oy = 0.f;
    #pragma unroll
    for (int i = 0; i < EE; ++i) {
        const float xv = __shfl((i & 1) ? xy : xx, i >> 1);
        const float2 w2 = *(const float2*)(WoutT + i * EE + lane * 2);
        ox += xv * w2.x;
        oy += xv * w2.y;
    }
    *(float2*)(out + (size_t)wj * EE + lane * 2) = make_float2(ox, oy);
}

extern "C" void kernel_launch(void* const* d_in, const int* in_sizes, int n_in,
                              void* d_out, int out_size, void* d_ws, size_t ws_size,
                              hipStream_t stream) {
    const float* query = (const float*)d_in[0];
    const float* key_t = (const float*)d_in[1];
    const float* value = (const float*)d_in[2];
    const float* W_lk  = (const float*)d_in[3];
    const float* W_rk  = (const float*)d_in[4];
    const float* W_lv  = (const float*)d_in[5];
    const float* W_rv  = (const float*)d_in[6];
    const float* W_out = (const float*)d_in[7];

    float* wt   = (float*)d_ws;                 // 5 * 16384 floats
    float* proj = wt + 5 * 16384;               // 4 * 1152 * 128 floats
    float* outp = (float*)d_out;

    // Host-side queries only (graph-capture-safe, deterministic every call).
    int coop = 0, ncu = 0, maxPerCU = 0;
    hipDeviceGetAttribute(&coop, hipDeviceAttributeCooperativeLaunch, 0);
    hipDeviceGetAttribute(&ncu, hipDeviceAttributeMultiprocessorCount, 0);
    hipOccupancyMaxActiveBlocksPerMultiprocessor(&maxPerCU, (const void*)fused_kernel, 256, 0);

    const int maxCoop = maxPerCU * ncu;
    if (coop && maxCoop >= 64) {
        const int grid = (maxCoop < CJOBS) ? maxCoop : CJOBS;   // <= 288
        void* args[] = {
            (void*)&query, (void*)&key_t, (void*)&value,
            (void*)&W_lk, (void*)&W_rk, (void*)&W_lv, (void*)&W_rv, (void*)&W_out,
            (void*)&wt, (void*)&proj, (void*)&outp,
        };
        hipLaunchCooperativeKernel((void*)fused_kernel, dim3(grid), dim3(256),
                                   args, 0, stream);
    } else {
        transpose_kernel<<<80, 256, 0, stream>>>(W_lk, W_rk, W_lv, W_rv, W_out, wt);
        proj_kernel<<<1152, 256, 0, stream>>>(query, key_t, value, wt, proj);
        attn_kernel<<<ROWS, 64, 0, stream>>>(proj, wt, outp);
    }
}